// Round 4
// baseline (441.946 us; speedup 1.0000x reference)
//
#include <hip/hip_runtime.h>
#include <math.h>

#define NB 1024  // number of dst-range buckets

// ---------------- CSR build: hist + scan + bucketed 2-phase scatter ----------

__global__ void k_init(int* counts, int n, int* bcount) {
  int i = blockIdx.x * blockDim.x + threadIdx.x;
  if (i < n) counts[i] = 1;   // self-loop
  if (i < NB) bcount[i] = 0;
}

__global__ void k_hist2(const int* __restrict__ dst, int E, int npb,
                        int* counts, int* bcount) {
  __shared__ int bh[NB];
  for (int i = threadIdx.x; i < NB; i += blockDim.x) bh[i] = 0;
  __syncthreads();
  int stride = gridDim.x * blockDim.x;
  for (int e = blockIdx.x * blockDim.x + threadIdx.x; e < E; e += stride) {
    int d = dst[e];
    atomicAdd(&counts[d], 1);
    atomicAdd(&bh[d / npb], 1);
  }
  __syncthreads();
  for (int i = threadIdx.x; i < NB; i += blockDim.x)
    if (bh[i]) atomicAdd(&bcount[i], bh[i]);
}

__global__ void k_scan_block(const int* __restrict__ in, int* __restrict__ out,
                             int* __restrict__ sums, int n) {
  __shared__ int tmp[1024];
  int tid = threadIdx.x;
  int i = blockIdx.x * 1024 + tid;
  int v = (i < n) ? in[i] : 0;
  int x = v;
  tmp[tid] = x;
  __syncthreads();
  for (int off = 1; off < 1024; off <<= 1) {
    int y = (tid >= off) ? tmp[tid - off] : 0;
    __syncthreads();
    x += y;
    tmp[tid] = x;
    __syncthreads();
  }
  if (i < n) out[i] = x - v;             // exclusive within block
  if (tid == 1023) sums[blockIdx.x] = x; // block total
}

__global__ void k_scan_sums(int* sums, int nb) {
  if (blockIdx.x == 0 && threadIdx.x == 0) {
    int run = 0;
    for (int i = 0; i < nb; i++) { int v = sums[i]; sums[i] = run; run += v; }
  }
}

__global__ void k_add_back(int* __restrict__ row_ptr, const int* __restrict__ sums,
                           int n, int total) {
  int i = blockIdx.x * blockDim.x + threadIdx.x;
  if (i < n) row_ptr[i] += sums[i >> 10];
  if (i == 0) row_ptr[n] = total;
}

// exclusive scan of NB bucket counts (single block of 1024 threads)
__global__ void k_scan_buckets(const int* __restrict__ bcount, int* __restrict__ boff,
                               int* __restrict__ bcur, int E) {
  __shared__ int tmp[NB];
  int tid = threadIdx.x;
  int v = bcount[tid];
  int x = v;
  tmp[tid] = x;
  __syncthreads();
  for (int off = 1; off < NB; off <<= 1) {
    int y = (tid >= off) ? tmp[tid - off] : 0;
    __syncthreads();
    x += y;
    tmp[tid] = x;
    __syncthreads();
  }
  int excl = x - v;
  boff[tid] = excl;
  bcur[tid] = excl;
  if (tid == NB - 1) boff[NB] = E;
}

// P1: append (src, ea, dst) records into per-bucket regions of tmp
__global__ void k_bucket_scatter(const int* __restrict__ src, const int* __restrict__ dst,
                                 const float* __restrict__ ea, int E, int npb,
                                 int* bcur, int4* __restrict__ tmp) {
  int stride = gridDim.x * blockDim.x;
  for (int e = blockIdx.x * blockDim.x + threadIdx.x; e < E; e += stride) {
    int d = dst[e];
    int b = d / npb;
    int pos = atomicAdd(&bcur[b], 1);
    tmp[pos] = make_int4(src[e], __float_as_int(ea[e]), d, 0);
  }
}

// P2: one block per bucket; write self-loops + scatter bucket edges into the
// bucket's contiguous eidx window using LDS cursors.
__global__ __launch_bounds__(256) void k_bucket_to_csr(
    const int4* __restrict__ tmp, const int* __restrict__ boff,
    const int* __restrict__ row_ptr, int npb, int N, int2* __restrict__ eidx) {
  __shared__ int cur[256];  // npb <= 256
  int b = blockIdx.x;
  int n0 = b * npb;
  int nn = N - n0;
  if (nn > npb) nn = npb;
  int t = threadIdx.x;
  if (t < nn) {
    int node = n0 + t;
    int rp = row_ptr[node];
    eidx[rp] = make_int2(node, __float_as_int(1.0f));  // self loop
    cur[t] = rp + 1;
  }
  __syncthreads();
  int i1 = boff[b + 1];
  for (int i = boff[b] + t; i < i1; i += 256) {
    int4 r = tmp[i];
    int pos = atomicAdd(&cur[r.z - n0], 1);
    eidx[pos] = make_int2(r.x, r.y);
  }
}

// ---------------- node linear (LDS-tiled GEMM): [xl|xr] = h @ [Wl|Wr] + [bl|br]

template<int CIN>
__global__ __launch_bounds__(256) void k_lin2_tiled(
    const float* __restrict__ h,
    const float* __restrict__ Wl, const float* __restrict__ bl,
    const float* __restrict__ Wr, const float* __restrict__ br,
    float* __restrict__ xl, float* __restrict__ xr, int N) {
  __shared__ float sW[64][128];  // 32 KB
  __shared__ float sH[64][64];   // 16 KB
  const int t = threadIdx.x;
  const int row0 = blockIdx.x * 64;
  const int c4 = (t & 31) * 4;
  const int rr = (t >> 5) * 8;

  float acc[8][4];
  #pragma unroll
  for (int r = 0; r < 8; r++)
    #pragma unroll
    for (int c = 0; c < 4; c++) acc[r][c] = 0.f;

  for (int kt = 0; kt < CIN; kt += 64) {
    __syncthreads();
    #pragma unroll
    for (int i = 0; i < 8; i++) {
      int flat = i * 1024 + t * 4;
      int k = flat >> 7, j = flat & 127;
      const float* Wsrc = (j < 64) ? Wl : Wr;
      *(float4*)&sW[k][j] = *(const float4*)&Wsrc[(size_t)(kt + k) * 64 + (j & 63)];
    }
    #pragma unroll
    for (int i = 0; i < 4; i++) {
      int flat = i * 1024 + t * 4;
      int r = flat >> 6, k = flat & 63;
      float4 v = make_float4(0.f, 0.f, 0.f, 0.f);
      if (row0 + r < N) v = *(const float4*)&h[(size_t)(row0 + r) * CIN + kt + k];
      *(float4*)&sH[r][k] = v;
    }
    __syncthreads();
    #pragma unroll 8
    for (int k = 0; k < 64; k++) {
      float4 w = *(float4*)&sW[k][c4];
      #pragma unroll
      for (int r = 0; r < 8; r++) {
        float hv = sH[rr + r][k];
        acc[r][0] = fmaf(hv, w.x, acc[r][0]);
        acc[r][1] = fmaf(hv, w.y, acc[r][1]);
        acc[r][2] = fmaf(hv, w.z, acc[r][2]);
        acc[r][3] = fmaf(hv, w.w, acc[r][3]);
      }
    }
  }

  const float* bsrc = (c4 < 64) ? bl : br;
  float bv[4];
  #pragma unroll
  for (int c = 0; c < 4; c++) bv[c] = bsrc[(c4 & 63) + c];
  float* o = (c4 < 64) ? xl : xr;
  #pragma unroll
  for (int r = 0; r < 8; r++) {
    int row = row0 + rr + r;
    if (row < N) {
      float4 v = make_float4(acc[r][0] + bv[0], acc[r][1] + bv[1],
                             acc[r][2] + bv[2], acc[r][3] + bv[3]);
      *(float4*)&o[(size_t)row * 64 + (c4 & 63)] = v;
    }
  }
}

// ---------------- per-dst-node edge pass: 4 edges/wave, online segment softmax

__global__ __launch_bounds__(256) void k_gat_edge(
    const float* __restrict__ xl, const float* __restrict__ xr,
    const int* __restrict__ row_ptr, const int2* __restrict__ eidx,
    const float* __restrict__ We, const float* __restrict__ att,
    const float* __restrict__ bias,
    float* __restrict__ out, int N) {
  int n = (blockIdx.x * blockDim.x + threadIdx.x) >> 6;  // one wave per node
  if (n >= N) return;
  int lane = threadIdx.x & 63;
  int g = lane >> 4;
  int cb = (lane & 15) * 4;

  float4 xi = *(const float4*)&xr[(size_t)n * 64 + cb];
  float4 we = *(const float4*)&We[cb];
  float4 at = *(const float4*)&att[cb];

  int e0 = row_ptr[n], e1 = row_ptr[n + 1];

  float m = -INFINITY, s = 0.f;
  float4 acc = make_float4(0.f, 0.f, 0.f, 0.f);

  int e = e0 + g;
  int2 meta = make_int2(0, 0);
  float4 xj = make_float4(0.f, 0.f, 0.f, 0.f);
  if (e < e1) {
    meta = eidx[e];
    xj = *(const float4*)&xl[(size_t)meta.x * 64 + cb];
  }

  while (e < e1) {
    int2 cm = meta;
    float4 cxj = xj;
    int en = e + 4;
    if (en < e1) {  // prefetch next edge for this group
      meta = eidx[en];
      xj = *(const float4*)&xl[(size_t)meta.x * 64 + cb];
    }
    float eav = __int_as_float(cm.y);
    float4 z;
    z.x = xi.x + cxj.x + eav * we.x;
    z.y = xi.y + cxj.y + eav * we.y;
    z.z = xi.z + cxj.z + eav * we.z;
    z.w = xi.w + cxj.w + eav * we.w;
    z.x = fmaxf(z.x, 0.f) + 0.2f * fminf(z.x, 0.f);
    z.y = fmaxf(z.y, 0.f) + 0.2f * fminf(z.y, 0.f);
    z.z = fmaxf(z.z, 0.f) + 0.2f * fminf(z.z, 0.f);
    z.w = fmaxf(z.w, 0.f) + 0.2f * fminf(z.w, 0.f);
    float p = z.x * at.x + z.y * at.y + z.z * at.z + z.w * at.w;
    #pragma unroll
    for (int off = 1; off < 16; off <<= 1) p += __shfl_xor(p, off, 64);
    float mn = fmaxf(m, p);
    float cs = __expf(m - mn);    // m=-inf first iter -> 0
    float cp = __expf(p - mn);
    s = s * cs + cp;
    acc.x = acc.x * cs + cp * cxj.x;
    acc.y = acc.y * cs + cp * cxj.y;
    acc.z = acc.z * cs + cp * cxj.z;
    acc.w = acc.w * cs + cp * cxj.w;
    m = mn;
    e = en;
  }

  #pragma unroll
  for (int off = 16; off <= 32; off <<= 1) {
    float mo = __shfl_xor(m, off, 64);
    float so = __shfl_xor(s, off, 64);
    float4 ao;
    ao.x = __shfl_xor(acc.x, off, 64);
    ao.y = __shfl_xor(acc.y, off, 64);
    ao.z = __shfl_xor(acc.z, off, 64);
    ao.w = __shfl_xor(acc.w, off, 64);
    float mn = fmaxf(m, mo);
    float cs = (m == -INFINITY) ? 0.f : __expf(m - mn);
    float co = (mo == -INFINITY) ? 0.f : __expf(mo - mn);
    s = s * cs + so * co;
    acc.x = acc.x * cs + ao.x * co;
    acc.y = acc.y * cs + ao.y * co;
    acc.z = acc.z * cs + ao.z * co;
    acc.w = acc.w * cs + ao.w * co;
    m = mn;
  }

  if (g == 0) {
    float inv = 1.0f / s;
    float4 o;
    o.x = acc.x * inv + bias[cb + 0];
    o.y = acc.y * inv + bias[cb + 1];
    o.z = acc.z * inv + bias[cb + 2];
    o.w = acc.w * inv + bias[cb + 3];
    *(float4*)&out[(size_t)n * 64 + cb] = o;
  }
}

// ---------------- launch ----------------

extern "C" void kernel_launch(void* const* d_in, const int* in_sizes, int n_in,
                              void* d_out, int out_size, void* d_ws, size_t ws_size,
                              hipStream_t stream) {
  const float* x    = (const float*)d_in[0];
  const int*   ei   = (const int*)d_in[1];
  const float* ea   = (const float*)d_in[2];
  const float* Wl0  = (const float*)d_in[3];
  const float* bl0  = (const float*)d_in[4];
  const float* Wr0  = (const float*)d_in[5];
  const float* br0  = (const float*)d_in[6];
  const float* We0  = (const float*)d_in[7];
  const float* att0 = (const float*)d_in[8];
  const float* bias0= (const float*)d_in[9];
  const float* Wl1  = (const float*)d_in[10];
  const float* bl1  = (const float*)d_in[11];
  const float* Wr1  = (const float*)d_in[12];
  const float* br1  = (const float*)d_in[13];
  const float* We1  = (const float*)d_in[14];
  const float* att1 = (const float*)d_in[15];
  const float* bias1= (const float*)d_in[16];

  const int N  = in_sizes[0] / 128;
  const int E  = in_sizes[1] / 2;
  const int ET = E + N;
  const int* src = ei;
  const int* dst = ei + E;
  const int npb = (N + NB - 1) / NB;   // nodes per bucket (49 for N=50000)

  char* w = (char*)d_ws;
  float* xl      = (float*)w; w += (size_t)N * 64 * 4;
  float* xr      = (float*)w; w += (size_t)N * 64 * 4;
  float* h1      = (float*)w; w += (size_t)N * 64 * 4;
  int*   row_ptr = (int*)w;   w += (size_t)(N + 2) * 4;
  int2*  eidx    = (int2*)w;  w += (size_t)ET * 8;
  int*   sums    = (int*)w;   w += 256;
  int*   bcount  = (int*)w;   w += NB * 4;
  int*   boff    = (int*)w;   w += (NB + 1) * 4;
  int*   bcur    = (int*)w;   w += NB * 4;
  // tmp aliases xl/xr: CSR build completes before layer-0 lin2 writes them
  int4*  tmp     = (int4*)xl;  // needs E*16 = 16 MB <= 25.6 MB (xl+xr)

  float* out = (float*)d_out;

  // ---- CSR build (same graph for both layers) ----
  int nb_scan = (N + 1023) / 1024;
  k_init<<<(N + 255) / 256, 256, 0, stream>>>(row_ptr, N, bcount);  // row_ptr as counts
  k_hist2<<<1024, 256, 0, stream>>>(dst, E, npb, row_ptr, bcount);
  {
    // scan node counts (in row_ptr) -> exclusive row_ptr
    // reuse eidx tail? use dedicated small buffers: scan in place via sums
  }
  k_scan_block<<<nb_scan, 1024, 0, stream>>>(row_ptr, row_ptr, sums, N);
  k_scan_sums<<<1, 64, 0, stream>>>(sums, nb_scan);
  k_add_back<<<(N + 255) / 256, 256, 0, stream>>>(row_ptr, sums, N, ET);
  k_scan_buckets<<<1, NB, 0, stream>>>(bcount, boff, bcur, E);
  k_bucket_scatter<<<1024, 256, 0, stream>>>(src, dst, ea, E, npb, bcur, tmp);
  k_bucket_to_csr<<<NB, 256, 0, stream>>>(tmp, boff, row_ptr, npb, N, eidx);

  // ---- layer 0: 128 -> 64 ----
  {
    int nblk = (N + 63) / 64;
    k_lin2_tiled<128><<<nblk, 256, 0, stream>>>(x, Wl0, bl0, Wr0, br0, xl, xr, N);
    k_gat_edge<<<(N + 3) / 4, 256, 0, stream>>>(xl, xr, row_ptr, eidx, We0, att0, bias0, h1, N);
  }
  // ---- layer 1: 64 -> 64 ----
  {
    int nblk = (N + 63) / 64;
    k_lin2_tiled<64><<<nblk, 256, 0, stream>>>(h1, Wl1, bl1, Wr1, br1, xl, xr, N);
    k_gat_edge<<<(N + 3) / 4, 256, 0, stream>>>(xl, xr, row_ptr, eidx, We1, att1, bias1, out, N);
  }
}

// Round 5
// 251.079 us; speedup vs baseline: 1.7602x; 1.7602x over previous
//
#include <hip/hip_runtime.h>
#include <math.h>

// nodes-per-bucket = 128 (pow2). nbk = ceil(N/128) buckets (<= 512 for N<=65536).
#define NPB_SHIFT 7
#define NPB 128
#define NBK_MAX 512

// ---------------- CSR build ----------------

__global__ void k_init_counts(int* counts, int n) {
  int i = blockIdx.x * blockDim.x + threadIdx.x;
  if (i < n) counts[i] = 1;  // self-loop
}

__global__ void k_hist(const int* __restrict__ dst, int E, int* counts) {
  int stride = gridDim.x * blockDim.x;
  for (int e = blockIdx.x * blockDim.x + threadIdx.x; e < E; e += stride)
    atomicAdd(&counts[dst[e]], 1);
}

__global__ void k_scan_block(const int* __restrict__ in, int* __restrict__ out,
                             int* __restrict__ sums, int n) {
  __shared__ int tmp[1024];
  int tid = threadIdx.x;
  int i = blockIdx.x * 1024 + tid;
  int v = (i < n) ? in[i] : 0;
  int x = v;
  tmp[tid] = x;
  __syncthreads();
  for (int off = 1; off < 1024; off <<= 1) {
    int y = (tid >= off) ? tmp[tid - off] : 0;
    __syncthreads();
    x += y;
    tmp[tid] = x;
    __syncthreads();
  }
  if (i < n) out[i] = x - v;             // exclusive within block
  if (tid == 1023) sums[blockIdx.x] = x; // block total
}

__global__ void k_scan_sums(int* sums, int nb) {
  if (blockIdx.x == 0 && threadIdx.x == 0) {
    int run = 0;
    for (int i = 0; i < nb; i++) { int v = sums[i]; sums[i] = run; run += v; }
  }
}

__global__ void k_add_back(int* __restrict__ row_ptr, const int* __restrict__ sums,
                           int n, int total) {
  int i = blockIdx.x * blockDim.x + threadIdx.x;
  if (i < n) row_ptr[i] += sums[i >> 10];
  if (i == 0) row_ptr[n] = total;
}

// bucket offsets derived from row_ptr: edges-only prefix = row_ptr[node] - node
__global__ void k_bucket_offsets(const int* __restrict__ row_ptr,
                                 int* __restrict__ boff, int* __restrict__ bcur,
                                 int nbk, int N) {
  int i = blockIdx.x * blockDim.x + threadIdx.x;
  if (i <= nbk) {
    int node = min(i << NPB_SHIFT, N);
    int v = row_ptr[node] - node;
    boff[i] = v;
    if (i < nbk) bcur[i] = v;
  }
}

// P1: LDS-aggregated bucket scatter. Each block owns a contiguous edge chunk;
// per-bucket counts in LDS, ONE global atomic per (block,bucket) reserves a
// dense run, then records are placed via a second LDS counter.
__global__ __launch_bounds__(256) void k_scatter_agg(
    const int* __restrict__ src, const int* __restrict__ dst,
    const float* __restrict__ ea, int E, int nbk, int chunk,
    int* bcur, int2* __restrict__ tmp) {
  __shared__ int lcnt[NBK_MAX], lcnt2[NBK_MAX], lbase[NBK_MAX];
  int t = threadIdx.x;
  for (int i = t; i < nbk; i += 256) { lcnt[i] = 0; lcnt2[i] = 0; }
  __syncthreads();
  int c0 = blockIdx.x * chunk;
  int c1 = min(E, c0 + chunk);
  for (int e = c0 + t; e < c1; e += 256)
    atomicAdd(&lcnt[dst[e] >> NPB_SHIFT], 1);
  __syncthreads();
  for (int i = t; i < nbk; i += 256) {
    int c = lcnt[i];
    lbase[i] = c ? atomicAdd(&bcur[i], c) : 0;
  }
  __syncthreads();
  for (int e = c0 + t; e < c1; e += 256) {
    int d = dst[e];
    int b = d >> NPB_SHIFT;
    int pos = lbase[b] + atomicAdd(&lcnt2[b], 1);
    // pack: dlocal (7b) << 20 | src (<2^20); ea bits in .y
    tmp[pos] = make_int2(((d & (NPB - 1)) << 20) | src[e], __float_as_int(ea[e]));
  }
}

// P2: one block per bucket; self-loops + bucket edges -> contiguous eidx window.
__global__ __launch_bounds__(256) void k_bucket_to_csr(
    const int2* __restrict__ tmp, const int* __restrict__ boff,
    const int* __restrict__ row_ptr, int N, int2* __restrict__ eidx) {
  __shared__ int cur[NPB];
  int b = blockIdx.x;
  int n0 = b << NPB_SHIFT;
  int nn = min(NPB, N - n0);
  int t = threadIdx.x;
  if (t < nn) {
    int node = n0 + t;
    int rp = row_ptr[node];
    eidx[rp] = make_int2(node, __float_as_int(1.0f));  // self loop
    cur[t] = rp + 1;
  }
  __syncthreads();
  int i1 = boff[b + 1];
  for (int i = boff[b] + t; i < i1; i += 256) {
    int2 r = tmp[i];
    int pos = atomicAdd(&cur[(r.x >> 20) & (NPB - 1)], 1);
    eidx[pos] = make_int2(r.x & 0xFFFFF, r.y);
  }
}

// ---------------- node linear (LDS-tiled GEMM): [xl|xr] = h @ [Wl|Wr] + [bl|br]

template<int CIN>
__global__ __launch_bounds__(256) void k_lin2_tiled(
    const float* __restrict__ h,
    const float* __restrict__ Wl, const float* __restrict__ bl,
    const float* __restrict__ Wr, const float* __restrict__ br,
    float* __restrict__ xl, float* __restrict__ xr, int N) {
  __shared__ float sW[64][128];  // 32 KB
  __shared__ float sH[64][64];   // 16 KB
  const int t = threadIdx.x;
  const int row0 = blockIdx.x * 64;
  const int c4 = (t & 31) * 4;
  const int rr = (t >> 5) * 8;

  float acc[8][4];
  #pragma unroll
  for (int r = 0; r < 8; r++)
    #pragma unroll
    for (int c = 0; c < 4; c++) acc[r][c] = 0.f;

  for (int kt = 0; kt < CIN; kt += 64) {
    __syncthreads();
    #pragma unroll
    for (int i = 0; i < 8; i++) {
      int flat = i * 1024 + t * 4;
      int k = flat >> 7, j = flat & 127;
      const float* Wsrc = (j < 64) ? Wl : Wr;
      *(float4*)&sW[k][j] = *(const float4*)&Wsrc[(size_t)(kt + k) * 64 + (j & 63)];
    }
    #pragma unroll
    for (int i = 0; i < 4; i++) {
      int flat = i * 1024 + t * 4;
      int r = flat >> 6, k = flat & 63;
      float4 v = make_float4(0.f, 0.f, 0.f, 0.f);
      if (row0 + r < N) v = *(const float4*)&h[(size_t)(row0 + r) * CIN + kt + k];
      *(float4*)&sH[r][k] = v;
    }
    __syncthreads();
    #pragma unroll 8
    for (int k = 0; k < 64; k++) {
      float4 w = *(float4*)&sW[k][c4];
      #pragma unroll
      for (int r = 0; r < 8; r++) {
        float hv = sH[rr + r][k];
        acc[r][0] = fmaf(hv, w.x, acc[r][0]);
        acc[r][1] = fmaf(hv, w.y, acc[r][1]);
        acc[r][2] = fmaf(hv, w.z, acc[r][2]);
        acc[r][3] = fmaf(hv, w.w, acc[r][3]);
      }
    }
  }

  const float* bsrc = (c4 < 64) ? bl : br;
  float bv[4];
  #pragma unroll
  for (int c = 0; c < 4; c++) bv[c] = bsrc[(c4 & 63) + c];
  float* o = (c4 < 64) ? xl : xr;
  #pragma unroll
  for (int r = 0; r < 8; r++) {
    int row = row0 + rr + r;
    if (row < N) {
      float4 v = make_float4(acc[r][0] + bv[0], acc[r][1] + bv[1],
                             acc[r][2] + bv[2], acc[r][3] + bv[3]);
      *(float4*)&o[(size_t)row * 64 + (c4 & 63)] = v;
    }
  }
}

// ---------------- per-dst-node edge pass: 4 edges/wave, online segment softmax

__global__ __launch_bounds__(256) void k_gat_edge(
    const float* __restrict__ xl, const float* __restrict__ xr,
    const int* __restrict__ row_ptr, const int2* __restrict__ eidx,
    const float* __restrict__ We, const float* __restrict__ att,
    const float* __restrict__ bias,
    float* __restrict__ out, int N) {
  int n = (blockIdx.x * blockDim.x + threadIdx.x) >> 6;  // one wave per node
  if (n >= N) return;
  int lane = threadIdx.x & 63;
  int g = lane >> 4;
  int cb = (lane & 15) * 4;

  float4 xi = *(const float4*)&xr[(size_t)n * 64 + cb];
  float4 we = *(const float4*)&We[cb];
  float4 at = *(const float4*)&att[cb];

  int e0 = row_ptr[n], e1 = row_ptr[n + 1];

  float m = -INFINITY, s = 0.f;
  float4 acc = make_float4(0.f, 0.f, 0.f, 0.f);

  int e = e0 + g;
  int2 meta = make_int2(0, 0);
  float4 xj = make_float4(0.f, 0.f, 0.f, 0.f);
  if (e < e1) {
    meta = eidx[e];
    xj = *(const float4*)&xl[(size_t)meta.x * 64 + cb];
  }

  while (e < e1) {
    int2 cm = meta;
    float4 cxj = xj;
    int en = e + 4;
    if (en < e1) {  // prefetch next edge for this group
      meta = eidx[en];
      xj = *(const float4*)&xl[(size_t)meta.x * 64 + cb];
    }
    float eav = __int_as_float(cm.y);
    float4 z;
    z.x = xi.x + cxj.x + eav * we.x;
    z.y = xi.y + cxj.y + eav * we.y;
    z.z = xi.z + cxj.z + eav * we.z;
    z.w = xi.w + cxj.w + eav * we.w;
    z.x = fmaxf(z.x, 0.f) + 0.2f * fminf(z.x, 0.f);
    z.y = fmaxf(z.y, 0.f) + 0.2f * fminf(z.y, 0.f);
    z.z = fmaxf(z.z, 0.f) + 0.2f * fminf(z.z, 0.f);
    z.w = fmaxf(z.w, 0.f) + 0.2f * fminf(z.w, 0.f);
    float p = z.x * at.x + z.y * at.y + z.z * at.z + z.w * at.w;
    #pragma unroll
    for (int off = 1; off < 16; off <<= 1) p += __shfl_xor(p, off, 64);
    float mn = fmaxf(m, p);
    float cs = __expf(m - mn);    // m=-inf first iter -> 0
    float cp = __expf(p - mn);
    s = s * cs + cp;
    acc.x = acc.x * cs + cp * cxj.x;
    acc.y = acc.y * cs + cp * cxj.y;
    acc.z = acc.z * cs + cp * cxj.z;
    acc.w = acc.w * cs + cp * cxj.w;
    m = mn;
    e = en;
  }

  #pragma unroll
  for (int off = 16; off <= 32; off <<= 1) {
    float mo = __shfl_xor(m, off, 64);
    float so = __shfl_xor(s, off, 64);
    float4 ao;
    ao.x = __shfl_xor(acc.x, off, 64);
    ao.y = __shfl_xor(acc.y, off, 64);
    ao.z = __shfl_xor(acc.z, off, 64);
    ao.w = __shfl_xor(acc.w, off, 64);
    float mn = fmaxf(m, mo);
    float cs = (m == -INFINITY) ? 0.f : __expf(m - mn);
    float co = (mo == -INFINITY) ? 0.f : __expf(mo - mn);
    s = s * cs + so * co;
    acc.x = acc.x * cs + ao.x * co;
    acc.y = acc.y * cs + ao.y * co;
    acc.z = acc.z * cs + ao.z * co;
    acc.w = acc.w * cs + ao.w * co;
    m = mn;
  }

  if (g == 0) {
    float inv = 1.0f / s;
    float4 o;
    o.x = acc.x * inv + bias[cb + 0];
    o.y = acc.y * inv + bias[cb + 1];
    o.z = acc.z * inv + bias[cb + 2];
    o.w = acc.w * inv + bias[cb + 3];
    *(float4*)&out[(size_t)n * 64 + cb] = o;
  }
}

// ---------------- launch ----------------

extern "C" void kernel_launch(void* const* d_in, const int* in_sizes, int n_in,
                              void* d_out, int out_size, void* d_ws, size_t ws_size,
                              hipStream_t stream) {
  const float* x    = (const float*)d_in[0];
  const int*   ei   = (const int*)d_in[1];
  const float* ea   = (const float*)d_in[2];
  const float* Wl0  = (const float*)d_in[3];
  const float* bl0  = (const float*)d_in[4];
  const float* Wr0  = (const float*)d_in[5];
  const float* br0  = (const float*)d_in[6];
  const float* We0  = (const float*)d_in[7];
  const float* att0 = (const float*)d_in[8];
  const float* bias0= (const float*)d_in[9];
  const float* Wl1  = (const float*)d_in[10];
  const float* bl1  = (const float*)d_in[11];
  const float* Wr1  = (const float*)d_in[12];
  const float* br1  = (const float*)d_in[13];
  const float* We1  = (const float*)d_in[14];
  const float* att1 = (const float*)d_in[15];
  const float* bias1= (const float*)d_in[16];

  const int N  = in_sizes[0] / 128;
  const int E  = in_sizes[1] / 2;
  const int ET = E + N;
  const int* src = ei;
  const int* dst = ei + E;
  const int nbk = (N + NPB - 1) >> NPB_SHIFT;   // buckets (391 for N=50000)

  char* w = (char*)d_ws;
  float* xl      = (float*)w; w += (size_t)N * 64 * 4;
  float* xr      = (float*)w; w += (size_t)N * 64 * 4;
  float* h1      = (float*)w; w += (size_t)N * 64 * 4;
  int*   row_ptr = (int*)w;   w += (size_t)(N + 2) * 4;
  int2*  eidx    = (int2*)w;  w += (size_t)ET * 8;
  int*   sums    = (int*)w;   w += 256;
  int*   boff    = (int*)w;   w += (NBK_MAX + 1) * 4;
  int*   bcur    = (int*)w;   w += NBK_MAX * 4;
  // tmp aliases xl: CSR build completes before layer-0 lin2 writes it
  int2*  tmp     = (int2*)xl;  // E*8 = 8 MB <= 12.8 MB (xl)

  float* out = (float*)d_out;

  // ---- CSR build (same graph for both layers) ----
  int nb_scan = (N + 1023) / 1024;
  k_init_counts<<<(N + 255) / 256, 256, 0, stream>>>(row_ptr, N);  // row_ptr as counts
  k_hist<<<1024, 256, 0, stream>>>(dst, E, row_ptr);
  k_scan_block<<<nb_scan, 1024, 0, stream>>>(row_ptr, row_ptr, sums, N);
  k_scan_sums<<<1, 64, 0, stream>>>(sums, nb_scan);
  k_add_back<<<(N + 255) / 256, 256, 0, stream>>>(row_ptr, sums, N, ET);
  k_bucket_offsets<<<(nbk + 256) / 256, 256, 0, stream>>>(row_ptr, boff, bcur, nbk, N);
  {
    int nblk = 128;
    int chunk = (E + nblk - 1) / nblk;
    k_scatter_agg<<<nblk, 256, 0, stream>>>(src, dst, ea, E, nbk, chunk, bcur, tmp);
  }
  k_bucket_to_csr<<<nbk, 256, 0, stream>>>(tmp, boff, row_ptr, N, eidx);

  // ---- layer 0: 128 -> 64 ----
  {
    int nblk = (N + 63) / 64;
    k_lin2_tiled<128><<<nblk, 256, 0, stream>>>(x, Wl0, bl0, Wr0, br0, xl, xr, N);
    k_gat_edge<<<(N + 3) / 4, 256, 0, stream>>>(xl, xr, row_ptr, eidx, We0, att0, bias0, h1, N);
  }
  // ---- layer 1: 64 -> 64 ----
  {
    int nblk = (N + 63) / 64;
    k_lin2_tiled<64><<<nblk, 256, 0, stream>>>(h1, Wl1, bl1, Wr1, br1, xl, xr, N);
    k_gat_edge<<<(N + 3) / 4, 256, 0, stream>>>(xl, xr, row_ptr, eidx, We1, att1, bias1, out, N);
  }
}